// Round 9
// baseline (185.632 us; speedup 1.0000x reference)
//
#include <hip/hip_runtime.h>
#include <math.h>

#define KK 40
#define HH 16
#define DD 128
#define NN 512
#define X0C 0.085f
#define LOG2E 1.4426950408889634f
#define LN2f 0.6931471805599453f
#define SCB 17.0f   // per-step 2^-17 scaling folded into P~
#define NBLK 512    // mega grid: 2 blocks/CU, co-residency guaranteed (34KB LDS)

// ws layout (float offsets). A-tables and PT stored TRANSPOSED ([o][r]).
enum {
  OFF_AW   = 0,                  // 512*16  fwd RNN drive
  OFF_BW   = OFF_AW + NN*HH,     // 512*16  bwd RNN drive
  OFF_WPB  = OFF_BW + NN*HH,     // 512*40  UwB @ W
  OFF_WBG  = OFF_WPB + NN*KK,    // 512*40  rowsum WlinB[words]
  OFF_TB   = OFF_WBG + NN*KK,    // 40*40
  OFF_H    = OFF_TB + KK*KK,     // 514*16
  OFF_HP   = OFF_H + 514*HH,     // 514*16
  OFF_A0   = OFF_HP + 514*HH,    // 40*40 x4 Taylor tables, layout [o][r]
  OFF_A1   = OFF_A0 + KK*KK,
  OFF_A2   = OFF_A1 + KK*KK,
  OFF_A3   = OFF_A2 + KK*KK,
  OFF_LA0  = OFF_A3 + KK*KK,     // 40
  OFF_FIN  = OFF_LA0 + KK,       // 40
  OFF_LACC = OFF_FIN + KK,       // 128 per-chunk log norms
  OFF_VL   = OFF_LACC + 128,     // 40 final direction
  OFF_CTR  = OFF_VL + 40,        // 8 uints: finisher ctr (slot 0)
  OFF_BAR  = OFF_CTR + 8,        // 8 uints: grid-barrier counters (slots 0..2)
  OFF_D    = OFF_BAR + 8,        // 64000*4 sigma-derivative tables (16B aligned)
  OFF_PT   = OFF_D + KK*KK*KK*4, // 511*1600 P~^T matrices, layout [i][o][r]
  WS_FLOATS = OFF_PT + 511*KK*KK
};

// smem arena carving (floats). Phase A0 reuses [0..5120) as scratch.
#define SM_A0   0        // 1600
#define SM_A1   1600
#define SM_A2   3200
#define SM_A3   4800
#define SM_TBL  6400     // 40*41 = 1640
#define SM_HL   8040     // 16
#define SM_HAL  8056
#define SM_HBL  8072
#define SM_WBG  8088     // 40
#define SM_PRA  8128     // 40
#define SM_AB   8168     // 40
#define SM_EL   8208     // 40
#define SM_EP   8248     // 4*40
#define SM_SIZE 8408

__device__ __forceinline__ float sigm(float x) {
  return 1.f / (1.f + __expf(-x));
}

// Grid barrier: arrive = threadfence + atomicAdd (release); wait = relaxed
// agent-scope atomic LOAD poll (non-RMW, non-serializing) + threadfence.
// Counters zeroed by hipMemsetAsync before launch (replay-safe).
__device__ __forceinline__ void gbar(float* ws, int k) {
  unsigned* ctr = (unsigned*)(ws + OFF_BAR) + k;
  __syncthreads();
  if (threadIdx.x == 0) {
    __threadfence();
    atomicAdd(ctr, 1u);
    while (__hip_atomic_load(ctr, __ATOMIC_RELAXED, __HIP_MEMORY_SCOPE_AGENT)
           < (unsigned)NBLK)
      __builtin_amdgcn_s_sleep(16);
    __threadfence();
  }
  __syncthreads();
}

__global__ __launch_bounds__(256) void mega(
    const float* __restrict__ E, const float* __restrict__ M, const float* __restrict__ MP,
    const float* __restrict__ T, const float* __restrict__ UA, const float* __restrict__ UB,
    const float* __restrict__ WlinA, const float* __restrict__ WlinB,
    const int* __restrict__ words, float* __restrict__ ws, float* __restrict__ out)
{
  __shared__ __align__(16) float smem[SM_SIZE];
  int tid = threadIdx.x;
  int lane = tid & 63;
  int b = blockIdx.x;
  int wv = (b << 2) + (tid >> 6);       // global wave id

  // ================= Phase A0: gathers + TB + D tables (553 tasks) =========
  for (int tb = b; tb < NN + 1 + KK; tb += NBLK) {
    __syncthreads();                    // smem reuse between strided tasks
    if (tb < NN) {
      float* wrow = smem;               // [128]
      int w = words[tb];
      if (tid < DD) wrow[tid] = E[w*DD + tid];
      if (tid < KK) {                   // WBg: coalesced strided sum
        const float* wb = WlinB + (size_t)w*(KK*KK) + tid;
        float acc = 0.f;
        #pragma unroll 8
        for (int s = 0; s < KK; ++s) acc += wb[s*KK];
        ws[OFF_WBG + tb*KK + tid] = acc;
      }
      __syncthreads();
      if (tid < 16) {                   // aw: M[:,17:145] @ w
        float acc = 0.f; const float* mr = M + tid*145 + 17;
        for (int d = 0; d < DD; ++d) acc += mr[d]*wrow[d];
        ws[OFF_AW + tb*HH + tid] = acc;
      } else if (tid < 32) {            // bw: MP[:,1:129] @ w
        int j = tid - 16; float acc = 0.f; const float* mr = MP + j*145 + 1;
        for (int d = 0; d < DD; ++d) acc += mr[d]*wrow[d];
        ws[OFF_BW + tb*HH + j] = acc;
      } else if (tid < 72) {            // wpartB: UB[:,145:273] @ w
        int o = tid - 32; float acc = 0.f; const float* ur = UB + o*289 + 145;
        for (int d = 0; d < DD; ++d) acc += ur[d]*wrow[d];
        ws[OFF_WPB + tb*KK + o] = acc;
      }
    } else if (tb == NN) {              // TB = UtB @ T^T
      float* Tl = smem;                 // [5120]
      for (int idx = tid; idx < KK*DD; idx += 256) Tl[idx] = T[idx];
      __syncthreads();
      for (int o2 = tid; o2 < KK*KK; o2 += 256) {
        int r = o2 / KK, s = o2 % KK;
        const float* ur = UB + r*289 + 145;
        float acc = 0.f;
        for (int d = 0; d < DD; ++d) acc += ur[d]*Tl[s*DD + d];
        ws[OFF_TB + o2] = acc;
      }
    } else {                            // sigma-derivative tables, r = tb-513
      int r = tb - (NN + 1);
      float* ur = smem;                 // [256]
      float* sa = smem + 256;           // [40]
      float* ta = smem + 296;           // [40]
      if (tid < DD) ur[tid] = UA[r*289 + 17 + tid];
      else if (tid < 2*DD) ur[tid] = UA[r*289 + 145 + (tid - DD)];
      __syncthreads();
      if (tid < KK) {
        float acc = 0.f; const float* tr = T + tid*DD;
        for (int d = 0; d < DD; ++d) acc += ur[d]*tr[d];
        sa[tid] = acc;
      } else if (tid >= 64 && tid < 64 + KK) {
        int s = tid - 64; float acc = 0.f; const float* tr = T + s*DD;
        for (int d = 0; d < DD; ++d) acc += ur[DD + d]*tr[d];
        ta[s] = acc;
      }
      __syncthreads();
      float4* dp = (float4*)(ws + OFF_D) + (size_t)r*1600;
      for (int st = tid; st < KK*KK; st += 256) {
        int s = st / KK, u = st - s*KK;
        float y = X0C + sa[s] + ta[u];
        float sg = sigm(y);
        float s1 = sg*(1.f - sg);
        float d2 = s1*(1.f - 2.f*sg)*0.5f;
        float d3 = s1*(1.f - 6.f*sg*(1.f - sg))*(1.f/6.f);
        dp[st] = make_float4(sg, s1, d2, d3);
      }
    }
  }

  gbar(ws, 0);

  // ================= Phase A: RNN (wv<32) + Taylor-MAC (wv 32..191) ========
  if (wv < 32) {
    // RNN: |dh'/dh| <= 0.04/step => 8 warm-up steps from 0: err ~7e-12.
    int row = lane & 15;
    int g = wv*4 + (lane >> 4);         // 0..127
    int dirb = g >> 6;                  // 0 fwd, 1 bwd
    int c = g & 63;
    const float* Mat = dirb ? MP : M;
    const float* drv = ws + (dirb ? OFF_BW : OFF_AW);
    float* outh = ws + (dirb ? OFF_HP : OFF_H);
    float base = Mat[row*145];
    int hoff = dirb ? 129 : 1;
    float mh[HH];
    #pragma unroll
    for (int k = 0; k < HH; ++k) mh[k] = Mat[row*145 + hoff + k];
    float dr[16];
    #pragma unroll
    for (int j = 0; j < 16; ++j) {
      int i = dirb ? (8*c + 15 - j) : (8*c - 8 + j);
      int ic = min(max(i, 0), NN - 1);
      dr[j] = drv[ic*HH + row];
    }
    float h = 0.f;
    #pragma unroll
    for (int j = 0; j < 16; ++j) {
      int i = dirb ? (8*c + 15 - j) : (8*c - 8 + j);
      bool valid = (i >= 0) && (i < NN);
      float acc = base + dr[j];
      #pragma unroll
      for (int k = 0; k < HH; ++k) acc += mh[k] * __shfl(h, k, 16);
      float h2 = sigm(acc);
      if (valid) h = h2;
      if (valid && j >= 8) outh[(i + 1)*HH + row] = h;
    }
    if (wv == 0 && lane < 16) {
      ws[OFF_H + lane] = 0.f;  ws[OFF_H + 513*HH + lane] = 0.f;
      ws[OFF_HP + lane] = 0.f; ws[OFF_HP + 513*HH + lane] = 0.f;
    }
  } else if (wv < 192) {
    // MAC: A_m[o][r] = sum_st D_m[r,st]*WlinA[o,st]; (o, r-quarter) per wave.
    int bb = wv - 32;
    int o = bb >> 2, q = bb & 3;
    int j = lane;
    float wreg[25];
    #pragma unroll
    for (int k = 0; k < 25; ++k) wreg[k] = WlinA[o*1600 + j + 64*k];
    for (int rr = 0; rr < 10; ++rr) {
      int r = q*10 + rr;
      const float4* dp = (const float4*)(ws + OFF_D) + (size_t)r*1600;
      float a0 = 0, a1 = 0, a2 = 0, a3 = 0;
      #pragma unroll
      for (int k = 0; k < 25; ++k) {
        float4 d = dp[j + 64*k];
        float wl = wreg[k];
        a0 += d.x*wl; a1 += d.y*wl; a2 += d.z*wl; a3 += d.w*wl;
      }
      #pragma unroll
      for (int m = 1; m <= 32; m <<= 1) {
        a0 += __shfl_xor(a0, m); a1 += __shfl_xor(a1, m);
        a2 += __shfl_xor(a2, m); a3 += __shfl_xor(a3, m);
      }
      if (j == 0) {                      // transposed write [o][r]
        ws[OFF_A0 + o*KK + r] = a0; ws[OFF_A1 + o*KK + r] = a1;
        ws[OFF_A2 + o*KK + r] = a2; ws[OFF_A3 + o*KK + r] = a3;
      }
    }
  }

  gbar(ws, 1);

  // ================= Phase B: per-position expansion (i = b, +512) =========
  for (int idx = tid; idx < KK*KK; idx += 256) {
    smem[SM_A0 + idx] = ws[OFF_A0 + idx];
    smem[SM_A1 + idx] = ws[OFF_A1 + idx];
    smem[SM_A2 + idx] = ws[OFF_A2 + idx];
    smem[SM_A3 + idx] = ws[OFF_A3 + idx];
    smem[SM_TBL + (idx / KK)*(KK + 1) + (idx % KK)] = ws[OFF_TB + idx];
  }
  for (int i = b; i < NN + 1; i += NBLK) {
    __syncthreads();
    bool hasE = (i < NN);
    if (tid < 16) {
      smem[SM_HL + tid]  = ws[OFF_H + i*HH + tid];
      smem[SM_HAL + tid] = (i >= 2) ? ws[OFF_HP + (i - 2)*HH + tid] : 0.f;
      smem[SM_HBL + tid] = (i >= 1) ? ws[OFF_HP + (i - 1)*HH + tid] : 0.f;
    }
    if (hasE && tid < KK) smem[SM_WBG + tid] = ws[OFF_WBG + i*KK + tid];
    __syncthreads();
    if (tid < KK) {
      const float* ua = UA + tid*289;
      float accA = ua[0];
      #pragma unroll
      for (int k2 = 0; k2 < HH; ++k2)
        accA += smem[SM_HL + k2]*ua[1 + k2] + smem[SM_HAL + k2]*ua[273 + k2];
      smem[SM_PRA + tid] = accA;
      if (hasE) {
        const float* ub = UB + tid*289;
        float accB = ub[0] + ((i >= 1) ? ws[OFF_WPB + (i - 1)*KK + tid] : 0.f);
        #pragma unroll
        for (int k2 = 0; k2 < HH; ++k2)
          accB += smem[SM_HL + k2]*ub[1 + k2] + smem[SM_HBL + k2]*ub[273 + k2];
        smem[SM_AB + tid] = accB;
      }
    }
    __syncthreads();
    if (hasE && tid < 4*KK) {
      int t = tid % KK, g = tid / KK;
      float accB = smem[SM_AB + t];
      float p = 0.f;
      #pragma unroll
      for (int j = 0; j < 10; ++j) {
        int u = g*10 + j;
        p += smem[SM_WBG + u] * sigm(accB + smem[SM_TBL + t*(KK + 1) + u]);
      }
      smem[SM_EP + g*KK + t] = p;
    }
    __syncthreads();
    if (tid < KK)
      smem[SM_EL + tid] = hasE ? (smem[SM_EP + tid] + smem[SM_EP + KK + tid] +
                                  smem[SM_EP + 2*KK + tid] + smem[SM_EP + 3*KK + tid]) : 0.f;
    __syncthreads();
    const float4* A0 = (const float4*)&smem[SM_A0];
    const float4* A1 = (const float4*)&smem[SM_A1];
    const float4* A2 = (const float4*)&smem[SM_A2];
    const float4* A3 = (const float4*)&smem[SM_A3];
    float4* pt4 = (float4*)(ws + OFF_PT + (size_t)(i - 1)*1600);
    for (int f = tid; f < 400; f += 256) {
      int o = f / 10, rb = (f - o*10)*4;
      float4 c0 = A0[f], c1 = A1[f], c2 = A2[f], c3 = A3[f];
      const float* p0 = (const float*)&c0; const float* p1 = (const float*)&c1;
      const float* p2 = (const float*)&c2; const float* p3 = (const float*)&c3;
      float res[4];
      float eo = smem[SM_EL + o];
      #pragma unroll
      for (int j = 0; j < 4; ++j) {
        int r = rb + j;
        float d = smem[SM_PRA + r] - X0C;
        float lp = ((p3[j]*d + p2[j])*d + p1[j])*d + p0[j];
        if (i == 0) {
          if (r == 0) ws[OFF_LA0 + o] = lp + eo;
          res[j] = 0.f;
        } else if (i == NN) {
          if (o == 1) ws[OFF_FIN + r] = lp;
          res[j] = 0.f;
        } else {
          res[j] = exp2f((lp + eo)*LOG2E - SCB);
        }
      }
      if (i > 0 && i < NN) pt4[f] = make_float4(res[0], res[1], res[2], res[3]);
    }
  }

  gbar(ws, 2);

  // ================= Phase C: register chunk-scan + finisher ===============
  if (wv < 128) {
    int c = wv;
    int o = min(lane, KK - 1);
    int s0 = 4*c;
    int len = min(4, 511 - s0);
    int w0 = (s0 >= 2) ? (s0 - 2) : 0;
    int warmN = s0 - w0;        // 0 (c==0) or 2
    int nst = warmN + len;
    const float* P = ws + OFF_PT;
    float lacc = 0.f;
    float v;
    if (c == 0) {
      float la = ws[OFF_LA0 + o];
      float m0 = la;
      #pragma unroll
      for (int m = 1; m <= 32; m <<= 1) m0 = fmaxf(m0, __shfl_xor(m0, m));
      v = __expf(la - m0);
      lacc = m0;
    } else {
      v = 1.f;
    }
    float pcA[KK], pcB[KK];
    int cnt = 0;

#define LOADCOL(buf, pi) do {                                         \
    const float4* g_ = (const float4*)(P + (size_t)(pi)*1600 + o*KK); \
    _Pragma("unroll")                                                 \
    for (int q_ = 0; q_ < 10; ++q_) *(float4*)&buf[4*q_] = g_[q_];    \
  } while (0)

#define MSTEP(cur, nxt, k) do {                                 \
    if ((k) + 1 < nst) LOADCOL(nxt, w0 + (k) + 1);              \
    float a0_ = 0, a1_ = 0, a2_ = 0, a3_ = 0;                   \
    _Pragma("unroll")                                           \
    for (int r_ = 0; r_ < KK; r_ += 4) {                        \
      a0_ += __shfl(v, r_ + 0, 64)*cur[r_ + 0];                 \
      a1_ += __shfl(v, r_ + 1, 64)*cur[r_ + 1];                 \
      a2_ += __shfl(v, r_ + 2, 64)*cur[r_ + 2];                 \
      a3_ += __shfl(v, r_ + 3, 64)*cur[r_ + 3];                 \
    }                                                           \
    float s_ = (a0_ + a1_) + (a2_ + a3_);                       \
    bool isReal_ = (k) >= warmN;                                \
    if (isReal_) ++cnt;                                         \
    bool bound_ = ((k) == warmN - 1) || ((k) == nst - 1) ||     \
                  (isReal_ && (((k) - warmN + 1) & 3) == 0);    \
    if (bound_) {                                               \
      float mx_ = s_;                                           \
      _Pragma("unroll")                                         \
      for (int m_ = 1; m_ <= 32; m_ <<= 1)                      \
        mx_ = fmaxf(mx_, __shfl_xor(mx_, m_));                  \
      v = s_ / mx_;                                             \
      if (isReal_) {                                            \
        lacc += __logf(mx_) + (float)cnt*(SCB*LN2f);            \
        cnt = 0;                                                \
      }                                                         \
    } else {                                                    \
      v = s_;                                                   \
    }                                                           \
  } while (0)

    LOADCOL(pcA, w0);
    int k = 0;
    while (k + 2 <= nst) {
      MSTEP(pcA, pcB, k);
      MSTEP(pcB, pcA, k + 1);
      k += 2;
    }
    if (k < nst) MSTEP(pcA, pcB, k);
#undef MSTEP
#undef LOADCOL

    if (lane == 0) ws[OFF_LACC + c] = lacc;
    if (c == 127 && lane < KK) ws[OFF_VL + lane] = v;
    __threadfence();
    int last = 0;
    if (lane == 0) {
      int old = atomicAdd((int*)(ws + OFF_CTR), 1);
      last = (old == 127);
    }
    last = __shfl(last, 0, 64);
    if (last) {
      __threadfence();
      float l = ws[OFF_LACC + lane] + ws[OFF_LACC + 64 + lane];
      #pragma unroll
      for (int m = 1; m <= 32; m <<= 1) l += __shfl_xor(l, m);
      float tv = (lane < KK) ? ws[OFF_VL + lane]*__expf(ws[OFF_FIN + lane]) : 0.f;
      #pragma unroll
      for (int m = 1; m <= 32; m <<= 1) tv += __shfl_xor(tv, m);
      if (lane == 0) out[0] = l + __logf(tv);
    }
  }
}

extern "C" void kernel_launch(void* const* d_in, const int* in_sizes, int n_in,
                              void* d_out, int out_size, void* d_ws, size_t ws_size,
                              hipStream_t stream) {
  const float* E     = (const float*)d_in[0];
  const float* M     = (const float*)d_in[1];
  const float* MP    = (const float*)d_in[2];
  const float* T     = (const float*)d_in[3];
  const float* UA    = (const float*)d_in[4];
  const float* UB    = (const float*)d_in[5];
  const float* WlinA = (const float*)d_in[6];
  const float* WlinB = (const float*)d_in[7];
  const int*   words = (const int*)d_in[8];
  float* ws  = (float*)d_ws;
  float* out = (float*)d_out;

  // zero finisher + barrier counters (16 uints) — replay-safe graph node
  hipMemsetAsync((char*)d_ws + OFF_CTR*sizeof(float), 0, 16*sizeof(unsigned), stream);
  mega<<<dim3(NBLK), dim3(256), 0, stream>>>(E, M, MP, T, UA, UB, WlinA, WlinB,
                                             words, ws, out);
}

// Round 10
// 63.975 us; speedup vs baseline: 2.9017x; 2.9017x over previous
//
#include <hip/hip_runtime.h>
#include <math.h>

#define KK 40
#define HH 16
#define DD 128
#define NN 512
#define X0C 0.085f
#define LOG2E 1.4426950408889634f
#define LN2f 0.6931471805599453f
#define SCB 17.0f   // per-step 2^-17 scaling folded into P~

// ws layout (float offsets). A-tables stored TRANSPOSED ([o][r]). No PT anymore.
enum {
  OFF_AW   = 0,                  // 512*16  fwd RNN drive
  OFF_BW   = OFF_AW + NN*HH,     // 512*16  bwd RNN drive
  OFF_WPB  = OFF_BW + NN*HH,     // 512*40  UwB @ W
  OFF_WBG  = OFF_WPB + NN*KK,    // 512*40  rowsum WlinB[words]
  OFF_TB   = OFF_WBG + NN*KK,    // 40*40
  OFF_H    = OFF_TB + KK*KK,     // 514*16
  OFF_HP   = OFF_H + 514*HH,     // 514*16
  OFF_A0   = OFF_HP + 514*HH,    // 40*40 x4 Taylor tables, layout [o][r]
  OFF_A1   = OFF_A0 + KK*KK,
  OFF_A2   = OFF_A1 + KK*KK,
  OFF_A3   = OFF_A2 + KK*KK,
  OFF_FIN  = OFF_A3 + KK*KK,     // 40
  OFF_LACC = OFF_FIN + KK,       // 128 per-chunk log norms
  OFF_VL   = OFF_LACC + 128,     // 40 final direction
  OFF_CTR  = OFF_VL + 40,        // 12 uints: main ctr (0) + 8 sub-ctrs (1..8)
  OFF_D    = OFF_CTR + 12,       // 64000*4 sigma-derivative tables (16B aligned)
  WS_FLOATS = OFF_D + KK*KK*KK*4
};

__device__ __forceinline__ float sigm(float x) {
  return 1.f / (1.f + __expf(-x));
}

// KA: fused prep. Blocks 0..511: per-word gathers; block 512: TB = UtB@T^T +
//     zero finisher counters; blocks 513..552: sigma-derivative tables.
__global__ __launch_bounds__(256) void ka_prep(
    const float* __restrict__ E, const float* __restrict__ M, const float* __restrict__ MP,
    const float* __restrict__ T, const float* __restrict__ UA, const float* __restrict__ UB,
    const float* __restrict__ WlinB, const int* __restrict__ words, float* __restrict__ ws)
{
  int b = blockIdx.x, t = threadIdx.x;
  if (b < NN) {
    __shared__ float wrow[DD];
    int w = words[b];
    if (t < DD) wrow[t] = E[w*DD + t];
    if (t < KK) {                       // WBg[b,u] = sum_s WlinB[w, s*40+u]
      const float* wb = WlinB + (size_t)w*(KK*KK) + t;
      float acc = 0.f;
      #pragma unroll 8
      for (int s = 0; s < KK; ++s) acc += wb[s*KK];
      ws[OFF_WBG + b*KK + t] = acc;
    }
    __syncthreads();
    if (t < 16) {                       // aw: M[:,17:145] @ w
      float acc = 0.f; const float* mr = M + t*145 + 17;
      for (int d = 0; d < DD; ++d) acc += mr[d]*wrow[d];
      ws[OFF_AW + b*HH + t] = acc;
    } else if (t < 32) {                // bw: MP[:,1:129] @ w
      int j = t - 16; float acc = 0.f; const float* mr = MP + j*145 + 1;
      for (int d = 0; d < DD; ++d) acc += mr[d]*wrow[d];
      ws[OFF_BW + b*HH + j] = acc;
    } else if (t < 72) {                // wpartB: UB[:,145:273] @ w
      int o = t - 32; float acc = 0.f; const float* ur = UB + o*289 + 145;
      for (int d = 0; d < DD; ++d) acc += ur[d]*wrow[d];
      ws[OFF_WPB + b*KK + o] = acc;
    }
  } else if (b == NN) {                 // TB = UtB @ T^T + counter reset
    if (t < 12) ((unsigned*)(ws + OFF_CTR))[t] = 0u;
    __shared__ float Tl[KK*DD];
    for (int idx = t; idx < KK*DD; idx += 256) Tl[idx] = T[idx];
    __syncthreads();
    for (int out = t; out < KK*KK; out += 256) {
      int r = out / KK, s = out % KK;
      const float* ur = UB + r*289 + 145;
      float acc = 0.f;
      for (int d = 0; d < DD; ++d) acc += ur[d]*Tl[s*DD + d];
      ws[OFF_TB + out] = acc;
    }
  } else {                              // sigma-derivative tables, r = b-513
    int r = b - (NN + 1);
    __shared__ float ur[2*DD];
    __shared__ float sa[KK], ta[KK];
    if (t < DD) ur[t] = UA[r*289 + 17 + t];                 // UsA row
    else if (t < 2*DD) ur[t] = UA[r*289 + 145 + (t - DD)];  // UtA row
    __syncthreads();
    if (t < KK) {
      float acc = 0.f; const float* tr = T + t*DD;
      for (int d = 0; d < DD; ++d) acc += ur[d]*tr[d];
      sa[t] = acc;
    } else if (t >= 64 && t < 64 + KK) {
      int s = t - 64; float acc = 0.f; const float* tr = T + s*DD;
      for (int d = 0; d < DD; ++d) acc += ur[DD + d]*tr[d];
      ta[s] = acc;
    }
    __syncthreads();
    float4* dp = (float4*)(ws + OFF_D) + (size_t)r*1600;
    for (int st = t; st < KK*KK; st += 256) {
      int s = st / KK, u = st - s*KK;
      float y = X0C + sa[s] + ta[u];
      float sg = sigm(y);
      float s1 = sg*(1.f - sg);
      float d2 = s1*(1.f - 2.f*sg)*0.5f;
      float d3 = s1*(1.f - 6.f*sg*(1.f - sg))*(1.f/6.f);
      dp[st] = make_float4(sg, s1, d2, d3);
    }
  }
}

// KB: fused RNN + Taylor-MAC. Blocks 0..31: chunk-parallel RNN scans.
// Blocks 32..191: A_m[o][r] reductions (TRANSPOSED write).
__global__ __launch_bounds__(64) void kb_rnn_mac(const float* __restrict__ M,
                                                 const float* __restrict__ MP,
                                                 const float* __restrict__ WlinA,
                                                 float* __restrict__ ws)
{
  int b = blockIdx.x;
  int lane = threadIdx.x;
  if (b < 32) {
    // RNN: |dh'/dh| <= 0.04/step => 8 warm-up steps from 0: err ~7e-12.
    int row = lane & 15;
    int g = b*4 + (lane >> 4);          // 0..127
    int dirb = g >> 6;                  // 0 fwd, 1 bwd
    int c = g & 63;
    const float* Mat = dirb ? MP : M;
    const float* drv = ws + (dirb ? OFF_BW : OFF_AW);
    float* out = ws + (dirb ? OFF_HP : OFF_H);
    float base = Mat[row*145];
    int hoff = dirb ? 129 : 1;
    float mh[HH];
    #pragma unroll
    for (int k = 0; k < HH; ++k) mh[k] = Mat[row*145 + hoff + k];
    float dr[16];
    #pragma unroll
    for (int j = 0; j < 16; ++j) {
      int i = dirb ? (8*c + 15 - j) : (8*c - 8 + j);
      int ic = min(max(i, 0), NN - 1);
      dr[j] = drv[ic*HH + row];
    }
    float h = 0.f;
    #pragma unroll
    for (int j = 0; j < 16; ++j) {
      int i = dirb ? (8*c + 15 - j) : (8*c - 8 + j);
      bool valid = (i >= 0) && (i < NN);
      float acc = base + dr[j];
      #pragma unroll
      for (int k = 0; k < HH; ++k) acc += mh[k] * __shfl(h, k, 16);
      float h2 = sigm(acc);
      if (valid) h = h2;
      if (valid && j >= 8) out[(i + 1)*HH + row] = h;
    }
    if (b == 0 && lane < 16) {
      ws[OFF_H + lane] = 0.f;  ws[OFF_H + 513*HH + lane] = 0.f;
      ws[OFF_HP + lane] = 0.f; ws[OFF_HP + 513*HH + lane] = 0.f;
    }
  } else {
    // MAC: A_m[o][r] = sum_st D_m[r,st]*WlinA[o,st]; (o, r-quarter) per block.
    int bb = b - 32;
    int o = bb >> 2, q = bb & 3;
    int j = lane;
    float wreg[25];
    #pragma unroll
    for (int k = 0; k < 25; ++k) wreg[k] = WlinA[o*1600 + j + 64*k];
    for (int rr = 0; rr < 10; ++rr) {
      int r = q*10 + rr;
      const float4* dp = (const float4*)(ws + OFF_D) + (size_t)r*1600;
      float a0 = 0, a1 = 0, a2 = 0, a3 = 0;
      #pragma unroll
      for (int k = 0; k < 25; ++k) {
        float4 d = dp[j + 64*k];
        float wl = wreg[k];
        a0 += d.x*wl; a1 += d.y*wl; a2 += d.z*wl; a3 += d.w*wl;
      }
      #pragma unroll
      for (int m = 1; m <= 32; m <<= 1) {
        a0 += __shfl_xor(a0, m); a1 += __shfl_xor(a1, m);
        a2 += __shfl_xor(a2, m); a3 += __shfl_xor(a3, m);
      }
      if (j == 0) {                      // transposed write [o][r]
        ws[OFF_A0 + o*KK + r] = a0; ws[OFF_A1 + o*KK + r] = a1;
        ws[OFF_A2 + o*KK + r] = a2; ws[OFF_A3 + o*KK + r] = a3;
      }
    }
  }
}

// KX: fused expand+scan+finish. 128 chunks; block c recomputes its own <=6
// P~ matrices in LDS (preA/accB/e from h/hp + staged A/TB/UA/UB), wave 0 runs
// the matvec scan from LDS. Hierarchical atomic finisher (max 16 same-addr).
__global__ __launch_bounds__(256) void kx_scan(const float* __restrict__ UA,
                                               const float* __restrict__ UB,
                                               float* __restrict__ ws,
                                               float* __restrict__ out)
{
  int c = blockIdx.x;           // 0..127
  int tid = threadIdx.x;
  int lane = tid & 63;
  int wvl = tid >> 6;
  __shared__ __align__(16) float sA0[KK*KK], sA1[KK*KK], sA2[KK*KK], sA3[KK*KK];
  __shared__ float sTB[KK*41];
  __shared__ float sP[KK*41];
  __shared__ float u0A[KK], UhA[KK][16], UpA[KK][16];
  __shared__ float u0B[KK], UhB[KK][16], UpB[KK][16];
  __shared__ float hv[6][16], hav[6][16], hbv[6][16];
  __shared__ float prA[6][KK], aB[6][KK], el[6][KK];
  __shared__ float sLA0[KK];
  __shared__ int lastFlag;

  int s0 = 4*c;
  int len = min(4, 511 - s0);
  int w0 = (s0 >= 2) ? s0 - 2 : 0;
  int warmN = s0 - w0;          // 0 (c==0) or 2
  int nst = warmN + len;        // number of scan steps = positions w0+1..w0+nst
  if (tid == 0) lastFlag = 0;

  for (int idx = tid; idx < KK*KK; idx += 256) {
    sA0[idx] = ws[OFF_A0 + idx]; sA1[idx] = ws[OFF_A1 + idx];
    sA2[idx] = ws[OFF_A2 + idx]; sA3[idx] = ws[OFF_A3 + idx];
    sTB[(idx/KK)*41 + (idx%KK)] = ws[OFF_TB + idx];
  }
  for (int idx = tid; idx < KK*33; idx += 256) {   // UA/UB needed columns
    int r = idx / 33, k = idx % 33;
    int col = (k == 0) ? 0 : ((k < 17) ? k : 273 + (k - 17));
    float a = UA[r*289 + col];
    float bb = UB[r*289 + col];
    if (k == 0)      { u0A[r] = a; u0B[r] = bb; }
    else if (k < 17) { UhA[r][k-1] = a; UhB[r][k-1] = bb; }
    else             { UpA[r][k-17] = a; UpB[r][k-17] = bb; }
  }
  for (int idx = tid; idx < nst*16; idx += 256) {  // h/hp rows for positions
    int p = idx / 16, k = idx % 16;
    int i = w0 + 1 + p;
    hv[p][k]  = ws[OFF_H + i*HH + k];
    hav[p][k] = (i >= 2) ? ws[OFF_HP + (i - 2)*HH + k] : 0.f;
    hbv[p][k] = ws[OFF_HP + (i - 1)*HH + k];       // i>=1 always
  }
  __syncthreads();
  for (int idx = tid; idx < nst*KK; idx += 256) {  // preA / accB (exact)
    int p = idx / KK, r = idx % KK;
    int i = w0 + 1 + p;
    float accA = u0A[r];
    float accB = u0B[r] + ws[OFF_WPB + (i - 1)*KK + r];
    #pragma unroll
    for (int k2 = 0; k2 < HH; ++k2) {
      accA += hv[p][k2]*UhA[r][k2] + hav[p][k2]*UpA[r][k2];
      accB += hv[p][k2]*UhB[r][k2] + hbv[p][k2]*UpB[r][k2];
    }
    prA[p][r] = accA; aB[p][r] = accB;
  }
  __syncthreads();
  for (int idx = tid; idx < nst*KK; idx += 256) {  // e[i,t]
    int p = idx / KK, t = idx % KK;
    int i = w0 + 1 + p;
    float accB = aB[p][t];
    const float* wbg = ws + OFF_WBG + i*KK;
    float e = 0.f;
    for (int u = 0; u < KK; ++u) e += wbg[u] * sigm(accB + sTB[t*41 + u]);
    el[p][t] = e;
  }
  if (c == 0 && tid < KK) {                        // LA0 (i=0, r=BOS=0)
    int o = tid;
    float accB0 = u0B[o];                          // h=hb=0, no wpb at i=0
    const float* wbg0 = ws + OFF_WBG;
    float e0 = 0.f;
    for (int u = 0; u < KK; ++u) e0 += wbg0[u] * sigm(accB0 + sTB[o*41 + u]);
    float d = u0A[0] - X0C;                        // preA(0, r) = u0A[r]
    float lp = ((sA3[o*KK]*d + sA2[o*KK])*d + sA1[o*KK])*d + sA0[o*KK];
    sLA0[o] = lp + e0;
  }
  if (c == 127 && tid >= 64 && tid < 64 + KK) {    // FIN (i=512, o=EOS=1)
    int r = tid - 64;
    float accA = u0A[r];
    #pragma unroll
    for (int k2 = 0; k2 < HH; ++k2)
      accA += ws[OFF_H + 512*HH + k2]*UhA[r][k2] + ws[OFF_HP + 510*HH + k2]*UpA[r][k2];
    float d = accA - X0C;
    float lp = ((sA3[KK + r]*d + sA2[KK + r])*d + sA1[KK + r])*d + sA0[KK + r];
    ws[OFF_FIN + r] = lp;
  }
  __syncthreads();

  // ---- scan (wave 0 owns v; all threads expand each step's matrix) ----
  float v = 1.f, lacc = 0.f;
  int cnt = 0;
  int o = min(lane, KK - 1);
  if (c == 0 && wvl == 0) {
    float la = sLA0[o];
    float m0 = la;
    #pragma unroll
    for (int m = 1; m <= 32; m <<= 1) m0 = fmaxf(m0, __shfl_xor(m0, m));
    v = __expf(la - m0);
    lacc = m0;
  }
  for (int k = 0; k < nst; ++k) {
    for (int f = tid; f < KK*KK; f += 256) {       // expand P~^T into sP[o][r]
      int oo = f / KK, r = f % KK;
      float d = prA[k][r] - X0C;
      float lp = ((sA3[f]*d + sA2[f])*d + sA1[f])*d + sA0[f];
      sP[oo*41 + r] = exp2f((lp + el[k][oo])*LOG2E - SCB);
    }
    __syncthreads();
    if (wvl == 0) {
      float a0 = 0, a1 = 0, a2 = 0, a3 = 0;
      #pragma unroll
      for (int r = 0; r < KK; r += 4) {
        a0 += __shfl(v, r + 0, 64)*sP[o*41 + r + 0];
        a1 += __shfl(v, r + 1, 64)*sP[o*41 + r + 1];
        a2 += __shfl(v, r + 2, 64)*sP[o*41 + r + 2];
        a3 += __shfl(v, r + 3, 64)*sP[o*41 + r + 3];
      }
      float s = (a0 + a1) + (a2 + a3);
      bool isReal = (k >= warmN);
      if (isReal) ++cnt;
      bool bound = (k == warmN - 1) || (k == nst - 1) ||
                   (isReal && (((k - warmN + 1) & 3) == 0));
      if (bound) {
        float mx = s;
        #pragma unroll
        for (int m = 1; m <= 32; m <<= 1) mx = fmaxf(mx, __shfl_xor(mx, m));
        v = s / mx;
        if (isReal) {
          lacc += __logf(mx) + (float)cnt*(SCB*LN2f);
          cnt = 0;
        }
      } else {
        v = s;
      }
    }
    __syncthreads();
  }
  if (wvl == 0) {
    if (lane == 0) ws[OFF_LACC + c] = lacc;
    if (c == 127 && lane < KK) ws[OFF_VL + lane] = v;
  }
  __syncthreads();

  // ---- hierarchical finisher arrival (max 16 same-address atomics) ----
  if (tid == 0) {
    __threadfence();
    unsigned* ctr = (unsigned*)(ws + OFF_CTR);
    unsigned s = atomicAdd(&ctr[1 + (c & 7)], 1u);
    if (s == 15u) {                  // 16th in sub-group
      unsigned m = atomicAdd(&ctr[0], 1u);
      if (m == 7u) lastFlag = 1;     // 8th sub-group: this block is last
    }
  }
  __syncthreads();
  if (lastFlag && wvl == 0) {
    __threadfence();
    float l = ws[OFF_LACC + lane] + ws[OFF_LACC + 64 + lane];
    #pragma unroll
    for (int m = 1; m <= 32; m <<= 1) l += __shfl_xor(l, m);
    float tv = (lane < KK) ? ws[OFF_VL + lane]*__expf(ws[OFF_FIN + lane]) : 0.f;
    #pragma unroll
    for (int m = 1; m <= 32; m <<= 1) tv += __shfl_xor(tv, m);
    if (lane == 0) out[0] = l + __logf(tv);
  }
}

extern "C" void kernel_launch(void* const* d_in, const int* in_sizes, int n_in,
                              void* d_out, int out_size, void* d_ws, size_t ws_size,
                              hipStream_t stream) {
  const float* E     = (const float*)d_in[0];
  const float* M     = (const float*)d_in[1];
  const float* MP    = (const float*)d_in[2];
  const float* T     = (const float*)d_in[3];
  const float* UA    = (const float*)d_in[4];
  const float* UB    = (const float*)d_in[5];
  const float* WlinA = (const float*)d_in[6];
  const float* WlinB = (const float*)d_in[7];
  const int*   words = (const int*)d_in[8];
  float* ws  = (float*)d_ws;
  float* out = (float*)d_out;

  ka_prep<<<dim3(NN + 1 + KK), dim3(256), 0, stream>>>(E, M, MP, T, UA, UB, WlinB, words, ws);
  kb_rnn_mac<<<dim3(192), dim3(64), 0, stream>>>(M, MP, WlinA, ws);
  kx_scan<<<dim3(128), dim3(256), 0, stream>>>(UA, UB, ws, out);
}